// Round 4
// baseline (2354.178 us; speedup 1.0000x reference)
//
#include <hip/hip_runtime.h>
#include <hip/hip_bf16.h>
#include <math.h>

#define B_    256
#define T_    60
#define TTOT  80
#define DIN   2048
#define D_    512
#define H_    512
#define G4    2048    // 4*H
#define M1    15360   // B_*T_

typedef __bf16 bf16x8 __attribute__((ext_vector_type(8)));
typedef __bf16 bf16x4 __attribute__((ext_vector_type(4)));
typedef float  f32x4  __attribute__((ext_vector_type(4)));

// ---------------- zero helper ----------------
__global__ void k_zero_u32(unsigned* __restrict__ p, int n) {
  int i = blockIdx.x * 256 + threadIdx.x;
  if (i < n) p[i] = 0u;
}

// ---------------- f32 -> bf16 convert ----------------
__global__ __launch_bounds__(256) void k_cvt(const float* __restrict__ s,
                                             __bf16* __restrict__ d, int n) {
  int i = (blockIdx.x * 256 + threadIdx.x) * 4;
  if (i >= n) return;
  float4 f = *(const float4*)(s + i);
  bf16x4 v;
  v[0] = (__bf16)f.x; v[1] = (__bf16)f.y; v[2] = (__bf16)f.z; v[3] = (__bf16)f.w;
  *(bf16x4*)(d + i) = v;
}

__global__ void k_bsum(const float* __restrict__ a, const float* __restrict__ b,
                       float* __restrict__ d) {
  int i = blockIdx.x * 256 + threadIdx.x;
  if (i < G4) d[i] = a[i] + b[i];
}

// ---------------- MFMA GEMM: C[m,n] = sum_k bf16(A'[m,k]) * B[n,k]  (+bias)
// A f32 [M][lda]; A' = alpha ? alpha[m/T_][k]*A : A.  B bf16 [N][K].
// 128x128 tile, BK=64, 4 waves, wave = 4x4 tiles of 16x16x32.
// XCD swizzle (T1): consecutive logical tiles -> same XCD for A-panel L2 reuse.
// XT: output row m remapped to (m%T_)*B_ + m/T_  (xW stored [t][b][n], bf16).
template<bool ALPHA, bool OUTBF, bool XT>
__global__ __launch_bounds__(256) void k_mm(const float* __restrict__ A, int lda,
                                            const __bf16* __restrict__ Bm,
                                            const float* __restrict__ bias0,
                                            const float* __restrict__ bias1,
                                            const float* __restrict__ alpha,
                                            void* __restrict__ Cout,
                                            int N, int K) {
  __shared__ __bf16 As[128 * 64];
  __shared__ __bf16 Bs[128 * 64];
  const int tid  = threadIdx.x;
  const int lane = tid & 63;
  const int wv   = tid >> 6;
  const int wm   = wv >> 1, wn = wv & 1;
  const int la   = lane & 15, lk = lane >> 4;

  // XCD-aware block swizzle (nwg % 8 == 0 in all uses here)
  int lin = blockIdx.y * gridDim.x + blockIdx.x;
  const int nwg = gridDim.x * gridDim.y;
  if ((nwg & 7) == 0) {
    int q = nwg >> 3;
    lin = (lin & 7) * q + (lin >> 3);
  }
  const int n0 = (lin % gridDim.x) * 128;
  const int m0 = (lin / gridDim.x) * 128;

  f32x4 acc[4][4];
  #pragma unroll
  for (int i = 0; i < 4; i++)
    #pragma unroll
    for (int j = 0; j < 4; j++) acc[i][j] = (f32x4){0.f, 0.f, 0.f, 0.f};

  for (int kt = 0; kt < K; kt += 64) {
    __syncthreads();
    #pragma unroll
    for (int i = 0; i < 4; i++) {          // stage A (f32 -> bf16)
      int idx = tid + i * 256;
      int row = idx >> 3, gk = idx & 7;
      const float* src = A + (size_t)(m0 + row) * lda + kt + gk * 8;
      float4 f0 = *(const float4*)src;
      float4 f1 = *(const float4*)(src + 4);
      if (ALPHA) {
        int b = (m0 + row) / T_;
        const float* ap = alpha + (size_t)b * K + kt + gk * 8;
        float4 a0 = *(const float4*)ap;
        float4 a1 = *(const float4*)(ap + 4);
        f0.x *= a0.x; f0.y *= a0.y; f0.z *= a0.z; f0.w *= a0.w;
        f1.x *= a1.x; f1.y *= a1.y; f1.z *= a1.z; f1.w *= a1.w;
      }
      bf16x8 v;
      v[0] = (__bf16)f0.x; v[1] = (__bf16)f0.y; v[2] = (__bf16)f0.z; v[3] = (__bf16)f0.w;
      v[4] = (__bf16)f1.x; v[5] = (__bf16)f1.y; v[6] = (__bf16)f1.z; v[7] = (__bf16)f1.w;
      *(bf16x8*)(As + row * 64 + ((gk ^ (row & 7)) << 3)) = v;
    }
    #pragma unroll
    for (int i = 0; i < 4; i++) {          // stage B (bf16 direct)
      int idx = tid + i * 256;
      int row = idx >> 3, gk = idx & 7;
      bf16x8 v = *(const bf16x8*)(Bm + (size_t)(n0 + row) * K + kt + gk * 8);
      *(bf16x8*)(Bs + row * 64 + ((gk ^ (row & 7)) << 3)) = v;
    }
    __syncthreads();
    #pragma unroll
    for (int ks = 0; ks < 2; ks++) {
      bf16x8 af[4], bfr[4];
      #pragma unroll
      for (int i = 0; i < 4; i++) {
        int row = wm * 64 + i * 16 + la;
        af[i] = *(const bf16x8*)(As + row * 64 + (((ks * 4 + lk) ^ (row & 7)) << 3));
      }
      #pragma unroll
      for (int j = 0; j < 4; j++) {
        int row = wn * 64 + j * 16 + la;
        bfr[j] = *(const bf16x8*)(Bs + row * 64 + (((ks * 4 + lk) ^ (row & 7)) << 3));
      }
      #pragma unroll
      for (int i = 0; i < 4; i++)
        #pragma unroll
        for (int j = 0; j < 4; j++)
          acc[i][j] = __builtin_amdgcn_mfma_f32_16x16x32_bf16(af[i], bfr[j], acc[i][j], 0, 0, 0);
    }
  }
  // epilogue: D layout col=lane&15, row=(lane>>4)*4+reg
  #pragma unroll
  for (int j = 0; j < 4; j++) {
    int col = n0 + wn * 64 + j * 16 + la;
    float bb = bias0[col] + (bias1 ? bias1[col] : 0.f);
    #pragma unroll
    for (int i = 0; i < 4; i++) {
      int rbase = m0 + wm * 64 + i * 16 + lk * 4;
      #pragma unroll
      for (int r = 0; r < 4; r++) {
        float v = acc[i][j][r] + bb;
        int m = rbase + r;
        size_t orow = XT ? ((size_t)(m % T_) * B_ + (m / T_)) : (size_t)m;
        if (OUTBF) ((__bf16*)Cout)[orow * N + col] = (__bf16)v;
        else       ((float*)Cout)[orow * N + col] = v;
      }
    }
  }
}

// ---------------- per-feature mean/var partials ----------------
__global__ __launch_bounds__(256) void k_stats_partial(const float* __restrict__ V,
                                                       float* __restrict__ part) {
  const int blk = blockIdx.x;
  const int tid = threadIdx.x;
  float s0 = 0.f, s1 = 0.f, q0 = 0.f, q1 = 0.f;
  const float* p = V + (size_t)blk * 64 * D_;
  for (int r = 0; r < 64; r++) {
    float a = p[(size_t)r * D_ + tid];
    float b = p[(size_t)r * D_ + tid + 256];
    s0 += a; q0 += a * a;
    s1 += b; q1 += b * b;
  }
  part[(size_t)blk * 1024 + tid]             = s0;
  part[(size_t)blk * 1024 + tid + 256]       = s1;
  part[(size_t)blk * 1024 + 512 + tid]       = q0;
  part[(size_t)blk * 1024 + 512 + tid + 256] = q1;
}

__global__ __launch_bounds__(512) void k_stats_final(const float* __restrict__ part,
                                                     float* __restrict__ stats) {
  const int d = threadIdx.x;
  float s = 0.f, q = 0.f;
  for (int r = 0; r < 240; r++) {
    s += part[(size_t)r * 1024 + d];
    q += part[(size_t)r * 1024 + 512 + d];
  }
  float mean = s * (1.f / 15360.f);
  float var  = q * (1.f / 15360.f) - mean * mean;
  stats[d]        = mean;
  stats[512 + d]  = 1.f / sqrtf(var + 1e-5f);
}

// ---------------- normalize (in place) + vscore ----------------
// w_h, w_s, b_attn cancel in softmax(axis=1) (per-row shift) -> omitted.
__global__ __launch_bounds__(512) void k_norm_vscore(float* __restrict__ V,
                                                     const float* __restrict__ stats,
                                                     const float* __restrict__ gamma,
                                                     const float* __restrict__ beta,
                                                     const float* __restrict__ w_attn,
                                                     float* __restrict__ vscore) {
  const int b = blockIdx.x, d = threadIdx.x;
  __shared__ float wv[T_];
  if (d < T_) wv[d] = w_attn[2 * H_ + d];
  __syncthreads();
  const float mean = stats[d], rstd = stats[512 + d];
  const float ga = gamma[d], be = beta[d];
  float vs = 0.f;
  float* p = V + (size_t)b * T_ * D_ + d;
  for (int t = 0; t < T_; t++) {
    float x = p[(size_t)t * D_];
    float xn = (x - mean) * rstd * ga + be;
    p[(size_t)t * D_] = xn;
    vs += wv[t] * xn;
  }
  vscore[(size_t)b * D_ + d] = vs;
}

// ---------------- alpha = softmax over 512, in place ----------------
__global__ __launch_bounds__(512) void k_softmax(float* __restrict__ a) {
  const int b = blockIdx.x, d = threadIdx.x;
  __shared__ float red[8];
  float x = a[(size_t)b * D_ + d];
  float m = x;
  #pragma unroll
  for (int o = 32; o >= 1; o >>= 1) m = fmaxf(m, __shfl_xor(m, o));
  if ((d & 63) == 0) red[d >> 6] = m;
  __syncthreads();
  float M = red[0];
  #pragma unroll
  for (int w = 1; w < 8; w++) M = fmaxf(M, red[w]);
  float e = expf(x - M);
  float s = e;
  #pragma unroll
  for (int o = 32; o >= 1; o >>= 1) s += __shfl_xor(s, o);
  __syncthreads();
  if ((d & 63) == 0) red[d >> 6] = s;
  __syncthreads();
  float S = 0.f;
  #pragma unroll
  for (int w = 0; w < 8; w++) S += red[w];
  a[(size_t)b * D_ + d] = e / S;
}

// ---------------- persistent recurrence: all 80 LSTM steps in one kernel ----
// 128 WGs x 256 thr = 512 waves. Wave = (b-tile b0, j-tile j0, all 4 gates).
// Group = 8 consecutive WGs = one b-tile (16 rows): h rows b0..b0+15 are
// produced AND consumed only inside the group -> 8-WG atomic barrier, no
// grid sync. W_hh fragments preloaded into ~256 VGPRs (reused 80x);
// c-tile lives in 4 VGPRs for the whole recurrence.
__device__ __forceinline__ float sigf(float x) { return 1.f / (1.f + expf(-x)); }

__global__ __launch_bounds__(256, 1) void k_rec(const __bf16* __restrict__ Whh,
                                                const __bf16* __restrict__ xW,   // [t][b][G4]
                                                const float* __restrict__ bsum,
                                                __bf16* __restrict__ hbuf,       // 2 * B_*H_
                                                float* __restrict__ out,
                                                unsigned* __restrict__ bar) {    // 16 ctr, zeroed
  const int tid  = threadIdx.x;
  const int lane = tid & 63;
  const int widx = tid >> 6;
  const int grp  = blockIdx.x >> 3;
  const int wgin = blockIdx.x & 7;
  const int b0   = grp * 16;
  const int j0   = (wgin * 4 + widx) * 16;
  const int la   = lane & 15, lk = lane >> 4;
  const int j    = j0 + la;

  // preload W_hh fragments (B operand: row = gate col n, contiguous k)
  bf16x8 wb[4][16];
  #pragma unroll
  for (int g = 0; g < 4; g++)
    #pragma unroll
    for (int ks = 0; ks < 16; ks++)
      wb[g][ks] = *(const bf16x8*)(Whh + (size_t)(g * H_ + j0 + la) * H_ + ks * 32 + lk * 8);

  float bs4[4];
  #pragma unroll
  for (int g = 0; g < 4; g++) bs4[g] = bsum[g * 512 + j];

  f32x4 creg = (f32x4){0.f, 0.f, 0.f, 0.f};
  unsigned tgt = 0;

  for (int t = 0; t < TTOT; t++) {
    const __bf16* hin  = hbuf + (size_t)(t & 1) * (B_ * H_);
    __bf16*       hout = hbuf + (size_t)((t + 1) & 1) * (B_ * H_);

    // prefetch per-step additive term (xW for t<60, biases after)
    float xg[4][4];
    if (t < T_) {
      #pragma unroll
      for (int r = 0; r < 4; r++) {
        const __bf16* xp = xW + ((size_t)t * B_ + b0 + lk * 4 + r) * G4 + j;
        #pragma unroll
        for (int g = 0; g < 4; g++) xg[r][g] = (float)xp[g * 512];
      }
    } else {
      #pragma unroll
      for (int r = 0; r < 4; r++)
        #pragma unroll
        for (int g = 0; g < 4; g++) xg[r][g] = bs4[g];
    }

    f32x4 acc[4];
    #pragma unroll
    for (int g = 0; g < 4; g++) acc[g] = (f32x4){0.f, 0.f, 0.f, 0.f};
    const __bf16* ap = hin + (size_t)(b0 + la) * H_ + lk * 8;
    #pragma unroll
    for (int ks = 0; ks < 16; ks++) {
      bf16x8 a = *(const bf16x8*)(ap + ks * 32);
      #pragma unroll
      for (int g = 0; g < 4; g++)
        acc[g] = __builtin_amdgcn_mfma_f32_16x16x32_bf16(a, wb[g][ks], acc[g], 0, 0, 0);
    }

    #pragma unroll
    for (int r = 0; r < 4; r++) {
      const int b = b0 + lk * 4 + r;
      float gi = sigf(acc[0][r] + xg[r][0]);
      float gf = sigf(acc[1][r] + xg[r][1]);
      float gg = tanhf(acc[2][r] + xg[r][2]);
      float go = sigf(acc[3][r] + xg[r][3]);
      float cn = gf * creg[r] + gi * gg;
      creg[r] = cn;
      float hn = go * tanhf(cn);
      hout[(size_t)b * H_ + j] = (__bf16)hn;
      out[((size_t)b * TTOT + t) * D_ + j] = hn;
    }

    // 8-WG group barrier (device-scope; h-tile exchange)
    __threadfence();
    __syncthreads();
    tgt += 8;
    if (tid == 0) {
      __hip_atomic_fetch_add(&bar[grp], 1u, __ATOMIC_ACQ_REL, __HIP_MEMORY_SCOPE_AGENT);
      while (__hip_atomic_load(&bar[grp], __ATOMIC_ACQUIRE, __HIP_MEMORY_SCOPE_AGENT) < tgt)
        __builtin_amdgcn_s_sleep(1);
      __threadfence();
    }
    __syncthreads();
  }
}

extern "C" void kernel_launch(void* const* d_in, const int* in_sizes, int n_in,
                              void* d_out, int out_size, void* d_ws, size_t ws_size,
                              hipStream_t stream) {
  const float* video  = (const float*)d_in[0];
  const float* W_enc  = (const float*)d_in[2];
  const float* b_enc  = (const float*)d_in[3];
  const float* gamma  = (const float*)d_in[4];
  const float* beta   = (const float*)d_in[5];
  const float* w_attn = (const float*)d_in[6];
  const float* W_ih   = (const float*)d_in[8];
  const float* W_hh   = (const float*)d_in[9];
  const float* b_ih   = (const float*)d_in[10];
  const float* b_hh   = (const float*)d_in[11];
  float* out = (float*)d_out;

  // workspace layout (float-sized slots; ~103 MB total)
  float*    base  = (float*)d_ws;
  float*    V     = base;                    size_t off = (size_t)M1 * D_;
  float*    part  = base + off;              off += 240 * 1024;
  float*    stats = base + off;              off += 1024;
  float*    alpha = base + off;              off += (size_t)B_ * D_;
  float*    bsum  = base + off;              off += G4;
  __bf16*   hbuf  = (__bf16*)(base + off);   off += (size_t)2 * B_ * H_ / 2;  // 131072 f
  unsigned* bar   = (unsigned*)(base + off); off += 64;                        // 16 used
  __bf16*   xWbf  = (__bf16*)(base + off);   off += (size_t)M1 * G4 / 2;
  __bf16*   Wencb = (__bf16*)(base + off);   off += (size_t)D_ * DIN / 2;
  __bf16*   Wihb  = (__bf16*)(base + off);   off += (size_t)G4 * H_ / 2;
  __bf16*   Whhb  = (__bf16*)(base + off);   off += (size_t)G4 * H_ / 2;

  // weight conversions + bias sum
  k_cvt<<<1024, 256, 0, stream>>>(W_enc, Wencb, D_ * DIN);
  k_cvt<<<1024, 256, 0, stream>>>(W_ih, Wihb, G4 * H_);
  k_cvt<<<1024, 256, 0, stream>>>(W_hh, Whhb, G4 * H_);
  k_bsum<<<8, 256, 0, stream>>>(b_ih, b_hh, bsum);

  // zero hbuf + bar (contiguous 131072 + 64 u32 slots; 16 bar ctrs used)
  k_zero_u32<<<513, 256, 0, stream>>>((unsigned*)hbuf, 131072 + 64);

  // encoder GEMM: V = video @ W_enc^T + b_enc  (M=15360,N=512,K=2048)
  k_mm<false, false, false><<<dim3(4, 120), 256, 0, stream>>>(
      video, DIN, Wencb, b_enc, nullptr, nullptr, V, D_, DIN);

  k_stats_partial<<<240, 256, 0, stream>>>(V, part);
  k_stats_final<<<1, 512, 0, stream>>>(part, stats);
  k_norm_vscore<<<B_, 512, 0, stream>>>(V, stats, gamma, beta, w_attn, alpha);
  k_softmax<<<B_, 512, 0, stream>>>(alpha);

  // xW[t][b][n] = ((alpha ⊙ Vnorm) @ W_ih^T + b_ih + b_hh), bf16, transposed
  k_mm<true, true, true><<<dim3(16, 120), 256, 0, stream>>>(
      V, D_, Wihb, b_ih, b_hh, alpha, (void*)xWbf, G4, D_);

  // all 80 recurrence steps in one persistent kernel
  k_rec<<<128, 256, 0, stream>>>(Whhb, xWbf, bsum, hbuf, out, bar);
}

// Round 5
// 862.155 us; speedup vs baseline: 2.7306x; 2.7306x over previous
//
#include <hip/hip_runtime.h>
#include <hip/hip_bf16.h>
#include <math.h>

#define B_    256
#define T_    60
#define TTOT  80
#define DIN   2048
#define D_    512
#define H_    512
#define G4    2048    // 4*H
#define M1    15360   // B_*T_

typedef __bf16 bf16x8 __attribute__((ext_vector_type(8)));
typedef __bf16 bf16x4 __attribute__((ext_vector_type(4)));
typedef float  f32x4  __attribute__((ext_vector_type(4)));

// ---------------- zero helper ----------------
__global__ void k_zero_u32(unsigned* __restrict__ p, int n) {
  int i = blockIdx.x * 256 + threadIdx.x;
  if (i < n) p[i] = 0u;
}

// ---------------- f32 -> bf16 convert ----------------
__global__ __launch_bounds__(256) void k_cvt(const float* __restrict__ s,
                                             __bf16* __restrict__ d, int n) {
  int i = (blockIdx.x * 256 + threadIdx.x) * 4;
  if (i >= n) return;
  float4 f = *(const float4*)(s + i);
  bf16x4 v;
  v[0] = (__bf16)f.x; v[1] = (__bf16)f.y; v[2] = (__bf16)f.z; v[3] = (__bf16)f.w;
  *(bf16x4*)(d + i) = v;
}

__global__ void k_bsum(const float* __restrict__ a, const float* __restrict__ b,
                       float* __restrict__ d) {
  int i = blockIdx.x * 256 + threadIdx.x;
  if (i < G4) d[i] = a[i] + b[i];
}

// ---------------- MFMA GEMM: C[m,n] = sum_k bf16(A'[m,k]) * B[n,k]  (+bias)
// A f32 [M][lda]; A' = alpha ? alpha[m/T_][k]*A : A.  B bf16 [N][K].
// 128x128 tile, BK=64, 4 waves, wave = 4x4 tiles of 16x16x32.
// XCD swizzle (T1). XT: output row m -> (m%T_)*B_ + m/T_ (xW stored [t][b][n]).
template<bool ALPHA, bool OUTBF, bool XT>
__global__ __launch_bounds__(256) void k_mm(const float* __restrict__ A, int lda,
                                            const __bf16* __restrict__ Bm,
                                            const float* __restrict__ bias0,
                                            const float* __restrict__ bias1,
                                            const float* __restrict__ alpha,
                                            void* __restrict__ Cout,
                                            int N, int K) {
  __shared__ __bf16 As[128 * 64];
  __shared__ __bf16 Bs[128 * 64];
  const int tid  = threadIdx.x;
  const int lane = tid & 63;
  const int wv   = tid >> 6;
  const int wm   = wv >> 1, wn = wv & 1;
  const int la   = lane & 15, lk = lane >> 4;

  int lin = blockIdx.y * gridDim.x + blockIdx.x;
  const int nwg = gridDim.x * gridDim.y;
  if ((nwg & 7) == 0) {
    int q = nwg >> 3;
    lin = (lin & 7) * q + (lin >> 3);
  }
  const int n0 = (lin % gridDim.x) * 128;
  const int m0 = (lin / gridDim.x) * 128;

  f32x4 acc[4][4];
  #pragma unroll
  for (int i = 0; i < 4; i++)
    #pragma unroll
    for (int j = 0; j < 4; j++) acc[i][j] = (f32x4){0.f, 0.f, 0.f, 0.f};

  for (int kt = 0; kt < K; kt += 64) {
    __syncthreads();
    #pragma unroll
    for (int i = 0; i < 4; i++) {          // stage A (f32 -> bf16)
      int idx = tid + i * 256;
      int row = idx >> 3, gk = idx & 7;
      const float* src = A + (size_t)(m0 + row) * lda + kt + gk * 8;
      float4 f0 = *(const float4*)src;
      float4 f1 = *(const float4*)(src + 4);
      if (ALPHA) {
        int b = (m0 + row) / T_;
        const float* ap = alpha + (size_t)b * K + kt + gk * 8;
        float4 a0 = *(const float4*)ap;
        float4 a1 = *(const float4*)(ap + 4);
        f0.x *= a0.x; f0.y *= a0.y; f0.z *= a0.z; f0.w *= a0.w;
        f1.x *= a1.x; f1.y *= a1.y; f1.z *= a1.z; f1.w *= a1.w;
      }
      bf16x8 v;
      v[0] = (__bf16)f0.x; v[1] = (__bf16)f0.y; v[2] = (__bf16)f0.z; v[3] = (__bf16)f0.w;
      v[4] = (__bf16)f1.x; v[5] = (__bf16)f1.y; v[6] = (__bf16)f1.z; v[7] = (__bf16)f1.w;
      *(bf16x8*)(As + row * 64 + ((gk ^ (row & 7)) << 3)) = v;
    }
    #pragma unroll
    for (int i = 0; i < 4; i++) {          // stage B (bf16 direct)
      int idx = tid + i * 256;
      int row = idx >> 3, gk = idx & 7;
      bf16x8 v = *(const bf16x8*)(Bm + (size_t)(n0 + row) * K + kt + gk * 8);
      *(bf16x8*)(Bs + row * 64 + ((gk ^ (row & 7)) << 3)) = v;
    }
    __syncthreads();
    #pragma unroll
    for (int ks = 0; ks < 2; ks++) {
      bf16x8 af[4], bfr[4];
      #pragma unroll
      for (int i = 0; i < 4; i++) {
        int row = wm * 64 + i * 16 + la;
        af[i] = *(const bf16x8*)(As + row * 64 + (((ks * 4 + lk) ^ (row & 7)) << 3));
      }
      #pragma unroll
      for (int j = 0; j < 4; j++) {
        int row = wn * 64 + j * 16 + la;
        bfr[j] = *(const bf16x8*)(Bs + row * 64 + (((ks * 4 + lk) ^ (row & 7)) << 3));
      }
      #pragma unroll
      for (int i = 0; i < 4; i++)
        #pragma unroll
        for (int j = 0; j < 4; j++)
          acc[i][j] = __builtin_amdgcn_mfma_f32_16x16x32_bf16(af[i], bfr[j], acc[i][j], 0, 0, 0);
    }
  }
  #pragma unroll
  for (int j = 0; j < 4; j++) {
    int col = n0 + wn * 64 + j * 16 + la;
    float bb = bias0[col] + (bias1 ? bias1[col] : 0.f);
    #pragma unroll
    for (int i = 0; i < 4; i++) {
      int rbase = m0 + wm * 64 + i * 16 + lk * 4;
      #pragma unroll
      for (int r = 0; r < 4; r++) {
        float v = acc[i][j][r] + bb;
        int m = rbase + r;
        size_t orow = XT ? ((size_t)(m % T_) * B_ + (m / T_)) : (size_t)m;
        if (OUTBF) ((__bf16*)Cout)[orow * N + col] = (__bf16)v;
        else       ((float*)Cout)[orow * N + col] = v;
      }
    }
  }
}

// ---------------- per-feature mean/var partials ----------------
__global__ __launch_bounds__(256) void k_stats_partial(const float* __restrict__ V,
                                                       float* __restrict__ part) {
  const int blk = blockIdx.x;
  const int tid = threadIdx.x;
  float s0 = 0.f, s1 = 0.f, q0 = 0.f, q1 = 0.f;
  const float* p = V + (size_t)blk * 64 * D_;
  for (int r = 0; r < 64; r++) {
    float a = p[(size_t)r * D_ + tid];
    float b = p[(size_t)r * D_ + tid + 256];
    s0 += a; q0 += a * a;
    s1 += b; q1 += b * b;
  }
  part[(size_t)blk * 1024 + tid]             = s0;
  part[(size_t)blk * 1024 + tid + 256]       = s1;
  part[(size_t)blk * 1024 + 512 + tid]       = q0;
  part[(size_t)blk * 1024 + 512 + tid + 256] = q1;
}

__global__ __launch_bounds__(512) void k_stats_final(const float* __restrict__ part,
                                                     float* __restrict__ stats) {
  const int d = threadIdx.x;
  float s = 0.f, q = 0.f;
  for (int r = 0; r < 240; r++) {
    s += part[(size_t)r * 1024 + d];
    q += part[(size_t)r * 1024 + 512 + d];
  }
  float mean = s * (1.f / 15360.f);
  float var  = q * (1.f / 15360.f) - mean * mean;
  stats[d]        = mean;
  stats[512 + d]  = 1.f / sqrtf(var + 1e-5f);
}

// ---------------- normalize (in place) + vscore ----------------
// w_h, w_s, b_attn cancel in softmax(axis=1) (per-row shift) -> omitted.
__global__ __launch_bounds__(512) void k_norm_vscore(float* __restrict__ V,
                                                     const float* __restrict__ stats,
                                                     const float* __restrict__ gamma,
                                                     const float* __restrict__ beta,
                                                     const float* __restrict__ w_attn,
                                                     float* __restrict__ vscore) {
  const int b = blockIdx.x, d = threadIdx.x;
  __shared__ float wv[T_];
  if (d < T_) wv[d] = w_attn[2 * H_ + d];
  __syncthreads();
  const float mean = stats[d], rstd = stats[512 + d];
  const float ga = gamma[d], be = beta[d];
  float vs = 0.f;
  float* p = V + (size_t)b * T_ * D_ + d;
  for (int t = 0; t < T_; t++) {
    float x = p[(size_t)t * D_];
    float xn = (x - mean) * rstd * ga + be;
    p[(size_t)t * D_] = xn;
    vs += wv[t] * xn;
  }
  vscore[(size_t)b * D_ + d] = vs;
}

// ---------------- alpha = softmax over 512, in place ----------------
__global__ __launch_bounds__(512) void k_softmax(float* __restrict__ a) {
  const int b = blockIdx.x, d = threadIdx.x;
  __shared__ float red[8];
  float x = a[(size_t)b * D_ + d];
  float m = x;
  #pragma unroll
  for (int o = 32; o >= 1; o >>= 1) m = fmaxf(m, __shfl_xor(m, o));
  if ((d & 63) == 0) red[d >> 6] = m;
  __syncthreads();
  float M = red[0];
  #pragma unroll
  for (int w = 1; w < 8; w++) M = fmaxf(M, red[w]);
  float e = expf(x - M);
  float s = e;
  #pragma unroll
  for (int o = 32; o >= 1; o >>= 1) s += __shfl_xor(s, o);
  __syncthreads();
  if ((d & 63) == 0) red[d >> 6] = s;
  __syncthreads();
  float S = 0.f;
  #pragma unroll
  for (int w = 0; w < 8; w++) S += red[w];
  a[(size_t)b * D_ + d] = e / S;
}

// ---------------- persistent recurrence, v2 ----------------
// 128 WGs; group = 8 WGs = one b-tile (16 rows). Cross-WG h exchange uses
// relaxed AGENT-scope atomics (sc-flagged, coherence-point ops) ordered by
// explicit s_waitcnt -- NO threadfence, NO L2 writeback/invalidate in loop.
// W_hh streamed from L2 each step (2 MB, resident per XCD); no reg preload.
__device__ __forceinline__ float sigf(float x) { return 1.f / (1.f + expf(-x)); }

__global__ __launch_bounds__(256) void k_rec(const __bf16* __restrict__ Whh,
                                             const __bf16* __restrict__ xW,   // [t][b][G4]
                                             const float* __restrict__ bsum,
                                             __bf16* __restrict__ hbuf,       // 2 * B_*H_
                                             float* __restrict__ out,
                                             unsigned* __restrict__ bar) {    // 16 ctr, 128B apart
  const int tid  = threadIdx.x;
  const int lane = tid & 63;
  const int widx = tid >> 6;
  const int grp  = blockIdx.x >> 3;
  const int wgin = blockIdx.x & 7;
  const int b0   = grp * 16;
  const int j0   = (wgin * 4 + widx) * 16;
  const int la   = lane & 15, lk = lane >> 4;
  const int j    = j0 + la;

  __shared__ __bf16 hsin[16 * 520];   // h-tile stage, row pad 520 (<=2-way conflicts)

  float bs4[4];
  #pragma unroll
  for (int g = 0; g < 4; g++) bs4[g] = bsum[g * 512 + j];

  f32x4 creg = (f32x4){0.f, 0.f, 0.f, 0.f};
  unsigned tgt = 0;

  // prefetch additive term for t=0
  float xg[4][4];
  #pragma unroll
  for (int r = 0; r < 4; r++) {
    const __bf16* xp = xW + ((size_t)(b0 + lk * 4 + r)) * G4 + j;
    #pragma unroll
    for (int g = 0; g < 4; g++) xg[r][g] = (float)xp[g * 512];
  }

  for (int t = 0; t < TTOT; t++) {
    const __bf16* hin  = hbuf + (size_t)(t & 1) * (B_ * H_);
    __bf16*       hout = hbuf + (size_t)((t + 1) & 1) * (B_ * H_);

    // stage h-tile (16x512 bf16) into LDS via coherent 8B loads (coalesced)
    #pragma unroll
    for (int rb = 0; rb < 8; rb++) {
      int flat = (tid + rb * 256) * 4;       // bf16 element index
      int row = flat >> 9, col = flat & 511;
      unsigned long long v = __hip_atomic_load(
          (const unsigned long long*)(hin + (size_t)(b0 + row) * H_ + col),
          __ATOMIC_RELAXED, __HIP_MEMORY_SCOPE_AGENT);
      *(unsigned long long*)(hsin + row * 520 + col) = v;
    }
    __syncthreads();

    f32x4 acc[4];
    #pragma unroll
    for (int g = 0; g < 4; g++) acc[g] = (f32x4){0.f, 0.f, 0.f, 0.f};
    #pragma unroll
    for (int ks = 0; ks < 16; ks++) {
      bf16x8 a = *(const bf16x8*)(hsin + la * 520 + ks * 32 + lk * 8);
      #pragma unroll
      for (int g = 0; g < 4; g++) {
        bf16x8 w = *(const bf16x8*)(Whh + (size_t)(g * H_ + j0 + la) * H_ + ks * 32 + lk * 8);
        acc[g] = __builtin_amdgcn_mfma_f32_16x16x32_bf16(a, w, acc[g], 0, 0, 0);
      }
    }

    // LSTM cell; h store via coherent 2B atomic stores, out via plain f32
    #pragma unroll
    for (int r = 0; r < 4; r++) {
      const int b = b0 + lk * 4 + r;
      float gi = sigf(acc[0][r] + xg[r][0]);
      float gf = sigf(acc[1][r] + xg[r][1]);
      float gg = tanhf(acc[2][r] + xg[r][2]);
      float go = sigf(acc[3][r] + xg[r][3]);
      float cn = gf * creg[r] + gi * gg;
      creg[r] = cn;
      float hn = go * tanhf(cn);
      __bf16 hb = (__bf16)hn;
      __hip_atomic_store((unsigned short*)(hout + (size_t)b * H_ + j),
                         *(unsigned short*)&hb,
                         __ATOMIC_RELAXED, __HIP_MEMORY_SCOPE_AGENT);
      out[((size_t)b * TTOT + t) * D_ + j] = hn;
    }

    // prefetch next step's additive term (hides under barrier wait)
    if (t + 1 < T_) {
      #pragma unroll
      for (int r = 0; r < 4; r++) {
        const __bf16* xp = xW + ((size_t)(t + 1) * B_ + b0 + lk * 4 + r) * G4 + j;
        #pragma unroll
        for (int g = 0; g < 4; g++) xg[r][g] = (float)xp[g * 512];
      }
    } else {
      #pragma unroll
      for (int r = 0; r < 4; r++)
        #pragma unroll
        for (int g = 0; g < 4; g++) xg[r][g] = bs4[g];
    }

    // group barrier: ensure h stores at coherence point, then count arrivals
    asm volatile("s_waitcnt vmcnt(0)" ::: "memory");
    __syncthreads();
    tgt += 8;
    if (tid == 0) {
      __hip_atomic_fetch_add(&bar[grp << 5], 1u,
                             __ATOMIC_RELAXED, __HIP_MEMORY_SCOPE_AGENT);
      unsigned v;
      do {
        __builtin_amdgcn_s_sleep(2);
        v = __hip_atomic_load(&bar[grp << 5],
                              __ATOMIC_RELAXED, __HIP_MEMORY_SCOPE_AGENT);
      } while (v < tgt);
    }
    __syncthreads();
  }
}

extern "C" void kernel_launch(void* const* d_in, const int* in_sizes, int n_in,
                              void* d_out, int out_size, void* d_ws, size_t ws_size,
                              hipStream_t stream) {
  const float* video  = (const float*)d_in[0];
  const float* W_enc  = (const float*)d_in[2];
  const float* b_enc  = (const float*)d_in[3];
  const float* gamma  = (const float*)d_in[4];
  const float* beta   = (const float*)d_in[5];
  const float* w_attn = (const float*)d_in[6];
  const float* W_ih   = (const float*)d_in[8];
  const float* W_hh   = (const float*)d_in[9];
  const float* b_ih   = (const float*)d_in[10];
  const float* b_hh   = (const float*)d_in[11];
  float* out = (float*)d_out;

  // workspace layout (float-sized slots; ~103 MB total)
  float*    base  = (float*)d_ws;
  float*    V     = base;                    size_t off = (size_t)M1 * D_;
  float*    part  = base + off;              off += 240 * 1024;
  float*    stats = base + off;              off += 1024;
  float*    alpha = base + off;              off += (size_t)B_ * D_;
  float*    bsum  = base + off;              off += G4;
  __bf16*   hbuf  = (__bf16*)(base + off);   off += (size_t)2 * B_ * H_ / 2;  // 131072 f
  unsigned* bar   = (unsigned*)(base + off); off += 512;                       // 16x128B
  __bf16*   xWbf  = (__bf16*)(base + off);   off += (size_t)M1 * G4 / 2;
  __bf16*   Wencb = (__bf16*)(base + off);   off += (size_t)D_ * DIN / 2;
  __bf16*   Wihb  = (__bf16*)(base + off);   off += (size_t)G4 * H_ / 2;
  __bf16*   Whhb  = (__bf16*)(base + off);   off += (size_t)G4 * H_ / 2;

  // weight conversions + bias sum
  k_cvt<<<1024, 256, 0, stream>>>(W_enc, Wencb, D_ * DIN);
  k_cvt<<<1024, 256, 0, stream>>>(W_ih, Wihb, G4 * H_);
  k_cvt<<<1024, 256, 0, stream>>>(W_hh, Whhb, G4 * H_);
  k_bsum<<<8, 256, 0, stream>>>(b_ih, b_hh, bsum);

  // zero hbuf + bar (contiguous 131072 + 512 u32 slots)
  k_zero_u32<<<515, 256, 0, stream>>>((unsigned*)hbuf, 131072 + 512);

  // encoder GEMM: V = video @ W_enc^T + b_enc  (M=15360,N=512,K=2048)
  k_mm<false, false, false><<<dim3(4, 120), 256, 0, stream>>>(
      video, DIN, Wencb, b_enc, nullptr, nullptr, V, D_, DIN);

  k_stats_partial<<<240, 256, 0, stream>>>(V, part);
  k_stats_final<<<1, 512, 0, stream>>>(part, stats);
  k_norm_vscore<<<B_, 512, 0, stream>>>(V, stats, gamma, beta, w_attn, alpha);
  k_softmax<<<B_, 512, 0, stream>>>(alpha);

  // xW[t][b][n] = ((alpha ⊙ Vnorm) @ W_ih^T + b_ih + b_hh), bf16, transposed
  k_mm<true, true, true><<<dim3(16, 120), 256, 0, stream>>>(
      V, D_, Wihb, b_ih, b_hh, alpha, (void*)xWbf, G4, D_);

  // all 80 recurrence steps in one persistent kernel
  k_rec<<<128, 256, 0, stream>>>(Whhb, xWbf, bsum, hbuf, out, bar);
}